// Round 11
// baseline (175.531 us; speedup 1.0000x reference)
//
#include <hip/hip_runtime.h>
#include <hip/hip_bf16.h>
#include <math.h>

// Problem constants
#define B 16
#define S 4096
#define D 64
#define NH 8
#define NBUCK 64          // buckets per hash
#define CHUNKS 512        // chunks per batch (NH * NBUCK)
#define BS 64             // bucket/chunk size

// fp16 hash: per-dot error sigma ~0.003. GAP = 0.03 = 10 sigma.
#define GAP_MFMA 0.03f

typedef __attribute__((ext_vector_type(8))) short s8_t;       // 8 bf16
typedef __attribute__((ext_vector_type(8))) _Float16 h8_t;    // 8 fp16
typedef __attribute__((ext_vector_type(4))) float f4_t;       // MFMA C/D
typedef __attribute__((ext_vector_type(2))) float f2_t;
typedef __attribute__((ext_vector_type(2))) unsigned int u32x2;

__device__ inline unsigned short f16_rne(float x) {
    union { _Float16 f; unsigned short u; } cv;
    cv.f = (_Float16)x;                       // v_cvt_f16_f32 (RNE)
    return cv.u;
}
__device__ inline unsigned int pack_f16_pair(float x0, float x1) {
    return (unsigned int)f16_rne(x0) | ((unsigned int)f16_rne(x1) << 16);
}
// truncation-pack two f32 into (bf16(x0) | bf16(x1)<<16): one v_perm_b32
__device__ inline unsigned int pack_trunc(float x0, float x1) {
    return __builtin_amdgcn_perm(__float_as_uint(x1), __float_as_uint(x0),
                                 0x07060302u);
}

// lgkm-only barrier: drains LDS writes but leaves register-destined global
// loads and fire-and-forget stores in flight.
#define BAR_LGKM() do {                                          \
    asm volatile("s_waitcnt lgkmcnt(0)" ::: "memory");           \
    __builtin_amdgcn_s_barrier();                                \
    asm volatile("" ::: "memory");                               \
} while (0)

// ds_read_b64_tr_b16 with compile-time offset (see pv_step).
template<int OFF>
__device__ inline u32x2 tr_read(unsigned int vaddr) {
    u32x2 d;
    asm volatile("ds_read_b64_tr_b16 %0, %1 offset:%c2"
                 : "=v"(d) : "v"(vaddr), "i"(OFF));
    return d;
}

// ---------------------------------------------------------------------------
// Kernel 1: MFMA hash (GEMM form), ALL-FP16 (see R7 comments).
// Top-2 selection over |v| (losing sign of argmax can never be second-best;
// near-tie cases fall under GAP and are f64-recomputed in sort).
// ---------------------------------------------------------------------------
#define HA_OFF 0          // A (R) : 256 rows x 144 B
#define HQ_OFF 36864      // Q     : 128 rows x 144 B
#define HLDS_TOT 55296
#define HSTR 144          // row stride bytes (64 fp16 + 8 pad)

__global__ __launch_bounds__(256, 2) void hash_kernel(
    const float* __restrict__ qk, const float* __restrict__ rot,
    float* __restrict__ out_buckets, int* __restrict__ bucket_ws,
    unsigned char* __restrict__ flag_ws)
{
    __shared__ char lds[HLDS_TOT];
    int tid = threadIdx.x;
    int wg = blockIdx.x;                       // 512 blocks, 512%8==0
    int orig = ((wg & 7) << 6) + (wg >> 3);    // XCD-contiguous remap
    int b    = orig >> 5;
    int tile = orig & 31;
    int token0 = tile * 128;

    // ---- stage A = R_all: A[m][f] = rot[f*256 + m], fp16 RNE ----
    {
        char* arow = lds + HA_OFF + tid * HSTR;
        #pragma unroll 4
        for (int f = 0; f < 64; f += 2) {
            float r0 = rot[(size_t)f * 256 + tid];
            float r1 = rot[(size_t)(f + 1) * 256 + tid];
            *(unsigned int*)(arow + f * 2) = pack_f16_pair(r0, r1);
        }
    }
    // ---- stage B = qk tile, fp16 RNE; coalesced 4-lanes-per-row ----
    {
        int wv0   = tid >> 6;
        int lane0 = tid & 63;
        int s_ = lane0 & 3;
        int rowA = wv0 * 32 + (lane0 >> 2);
        int rowB = rowA + 16;
        const float4* qA = (const float4*)(qk + ((size_t)b * S + token0 + rowA) * D);
        const float4* qB = (const float4*)(qk + ((size_t)b * S + token0 + rowB) * D);
        float4 a4[4], b4[4];
        #pragma unroll
        for (int n = 0; n < 4; ++n) { a4[n] = qA[n * 4 + s_]; b4[n] = qB[n * 4 + s_]; }

        char* qhA = lds + HQ_OFF + rowA * HSTR;
        char* qhB = lds + HQ_OFF + rowB * HSTR;
        #pragma unroll
        for (int n = 0; n < 4; ++n) {
            *(uint2*)(qhA + n * 32 + s_ * 8) =
                make_uint2(pack_f16_pair(a4[n].x, a4[n].y),
                           pack_f16_pair(a4[n].z, a4[n].w));
            *(uint2*)(qhB + n * 32 + s_ * 8) =
                make_uint2(pack_f16_pair(b4[n].x, b4[n].y),
                           pack_f16_pair(b4[n].z, b4[n].w));
        }
    }
    __syncthreads();

    int wv   = tid >> 6;
    int lane = tid & 63;
    int quad = lane >> 4;
    int cc   = lane & 15;

    for (int nt = 0; nt < 2; ++nt) {
        int ntg = wv * 2 + nt;            // 0..7 (16-token groups)
        const char* qr = lds + HQ_OFF + (ntg * 16 + cc) * HSTR + quad * 16;
        h8_t b0 = *(const h8_t*)(qr);
        h8_t b1 = *(const h8_t*)(qr + 64);

        float v1 = -3e38f, v2 = -3e38f;
        int i1 = 0;

        for (int mt = 0; mt < 16; ++mt) {
            const char* arow = lds + HA_OFF + (mt * 16 + cc) * HSTR + quad * 16;
            h8_t a0 = *(const h8_t*)(arow);
            h8_t a1 = *(const h8_t*)(arow + 64);
            f4_t acc = (f4_t){0.f, 0.f, 0.f, 0.f};
            acc = __builtin_amdgcn_mfma_f32_16x16x32_f16(a0, b0, acc, 0, 0, 0);
            acc = __builtin_amdgcn_mfma_f32_16x16x32_f16(a1, b1, acc, 0, 0, 0);

            if ((mt & 1) == 0) { v1 = -3e38f; v2 = -3e38f; i1 = 0; }
            int ibase = ((mt & 1) << 4) + (quad << 2);
            #pragma unroll
            for (int r = 0; r < 4; ++r) {
                float a_ = __builtin_fabsf(acc[r]);
                int ip = ibase + r + (int)((__float_as_uint(acc[r]) >> 31) << 5);
                v2 = fmaxf(v2, fminf(a_, v1));
                if (a_ > v1) { v1 = a_; i1 = ip; }
            }

            if (mt & 1) {
                // butterfly merge across the 4 quads (lane bits 4,5)
                #pragma unroll
                for (int off = 16; off <= 32; off <<= 1) {
                    float ov1 = __shfl_xor(v1, off, 64);
                    float ov2 = __shfl_xor(v2, off, 64);
                    int   oi1 = __shfl_xor(i1, off, 64);
                    float nv2 = fmaxf(fmaxf(v2, ov2), fminf(v1, ov1));
                    if (ov1 > v1) { v1 = ov1; i1 = oi1; }
                    v2 = nv2;
                }
                if (quad == 0) {
                    int h = mt >> 1;
                    int tok = token0 + ntg * 16 + cc;
                    size_t idx = (size_t)(b * NH + h) * S + tok;
                    bucket_ws[idx] = i1;
                    out_buckets[idx] = (float)(i1 + h * NBUCK);
                    flag_ws[idx] = (v1 - v2 < GAP_MFMA) ? 1 : 0;  // fire-and-forget
                }
            }
        }
    }
}

// ---------------------------------------------------------------------------
// Kernel 2: FUSED sort + exact fixup per (b,h). 1024 threads (16 waves):
// the grid is only 128 blocks (half the CUs idle), so per-block LATENCY is
// the whole cost. vs the 512-thread version: serial scatter depth 8 -> 4,
// staging/histogram loops halve, f64 fixup spreads over 2x threads. Prefix
// scan extends to 16 wave-histograms. Ballot-dedup histogram retained.
// ---------------------------------------------------------------------------
__global__ __launch_bounds__(1024) void sort_kernel(
    const int* __restrict__ bucket_ws, int* __restrict__ st_ws,
    const float* __restrict__ qk, const float* __restrict__ rot,
    const unsigned char* __restrict__ flag_ws, float* __restrict__ out_buckets)
{
    __shared__ int sb[S];              // 16 KB
    __shared__ int hist[16][64];       // 4 KB
    __shared__ int bpref[64];
    __shared__ int woff[16][64];       // 4 KB
    __shared__ float rots[2048];       // 8 KB: [f][i] slice for this h
    __shared__ int list[1024];         // 4 KB
    __shared__ int cnt;

    int tid  = threadIdx.x;
    int wv   = tid >> 6;               // 0..15
    int lane = tid & 63;
    int bh   = blockIdx.x;
    int b    = bh >> 3;
    int h    = bh & 7;
    int base = bh * S;

    hist[wv][lane] = 0;
    if (tid == 0) cnt = 0;
    __syncthreads();

    int qbase = wv * 256;
    #pragma unroll
    for (int i = 0; i < 4; ++i) {
        int t = qbase + i * 64 + lane;
        sb[t] = bucket_ws[base + t];
    }
    // flag compaction: 4 bytes per thread
    {
        unsigned int fv = *(const unsigned int*)(flag_ws + base + tid * 4);
        if (fv) {
            #pragma unroll
            for (int e = 0; e < 4; ++e)
                if ((fv >> (8 * e)) & 0xffu) {
                    int slot = atomicAdd(&cnt, 1);
                    if (slot < 1024) list[slot] = tid * 4 + e;
                }
        }
    }
    // stage rot slice for this h: rots[f*32+i] = rot[f*256 + h*32 + i]
    #pragma unroll
    for (int k = 0; k < 2; ++k) {
        int idx = tid * 2 + k;
        rots[idx] = rot[(size_t)(idx >> 5) * 256 + h * 32 + (idx & 31)];
    }
    __syncthreads();

    int n = cnt; if (n > 1024) n = 1024;
    for (int j = tid; j < n; j += 1024) {
        int t = list[j];
        const float* row = qk + ((size_t)b * S + t) * D;
        double acc[32];
        #pragma unroll
        for (int i = 0; i < 32; ++i) acc[i] = 0.0;
        for (int f = 0; f < 64; ++f) {
            double x = (double)row[f];
            const float* rr = rots + f * 32;
            #pragma unroll
            for (int i = 0; i < 32; ++i)
                acc[i] = __fma_rn(x, (double)rr[i], acc[i]);
        }
        double best = acc[0]; int bi = 0;
        double worst = acc[0]; int wi = 0;
        #pragma unroll
        for (int i = 1; i < 32; ++i) {
            if (acc[i] > best)  { best = acc[i]; bi = i; }
            if (acc[i] < worst) { worst = acc[i]; wi = i; }
        }
        int bucket = (-worst > best) ? (32 + wi) : bi;
        sb[t] = bucket;
        out_buckets[base + t] = (float)(bucket + h * NBUCK);
    }
    __syncthreads();

    // histogram over (corrected) sb -- ballot-dedup
    #pragma unroll
    for (int i = 0; i < 4; ++i) {
        int v = sb[qbase + i * 64 + lane];
        unsigned long long m = ~0ULL;
        #pragma unroll
        for (int bit = 0; bit < 6; ++bit) {
            unsigned long long bm = __ballot((v >> bit) & 1);
            m &= ((v >> bit) & 1) ? bm : ~bm;
        }
        unsigned long long below = (lane == 63) ? ~0ULL >> 1
                                 : ((1ULL << lane) - 1ULL);
        if ((m & below) == 0ULL)
            atomicAdd(&hist[wv][v], __popcll(m));
    }
    __syncthreads();

    if (wv == 0) {
        int total = 0;
        #pragma unroll
        for (int w = 0; w < 16; ++w) total += hist[w][lane];
        int x = total;
        #pragma unroll
        for (int off = 1; off < 64; off <<= 1) {
            int y = __shfl_up(x, off, 64);
            if (lane >= off) x += y;
        }
        bpref[lane] = x - total;
    }
    __syncthreads();
    {
        int o = bpref[lane];
        #pragma unroll
        for (int w2 = 0; w2 < 16; ++w2) {
            if (w2 < wv) o += hist[w2][lane];
        }
        woff[wv][lane] = o;
    }
    __syncthreads();

    for (int g = 0; g < 4; ++g) {
        int t = qbase + g * 64 + lane;
        int v = sb[t];

        unsigned long long m = ~0ULL;
        #pragma unroll
        for (int bit = 0; bit < 6; ++bit) {
            unsigned long long bm = __ballot((v >> bit) & 1);
            m &= ((v >> bit) & 1) ? bm : ~bm;
        }
        unsigned long long below = (lane == 63) ? ~0ULL >> 1
                                 : ((1ULL << lane) - 1ULL);
        int rank = __popcll(m & below);
        int cnt2 = __popcll(m);

        int pos = woff[wv][v] + rank;
        st_ws[base + pos] = t;

        if ((m & below) == 0ULL)
            woff[wv][v] += cnt2;
    }
}

// ---------------------------------------------------------------------------
// Kernel 3: per-chunk attention (unchanged from R10: hoisted barrier,
// max-free log2 softmax, fp8 e4m3 O partials).
// ---------------------------------------------------------------------------
#define OFF_VT 18432
#define OFF_NRM 35840
#define OFF_TKX 36352
#define OFF_PINV 36864
#define LDS_TOT 37120
#define KSTRB 144     // K row stride bytes (72 bf16), 16B-aligned, 36 dw
#define PSTRB 272     // P row stride bytes (136 bf16), 68 dw

// one PV phase: P b128 + 8 tr reads + 4 MFMAs
template<int KC>
__device__ inline void pv_step(const char* lds, unsigned vaddr,
                               int wv, int cc, int quad, f4_t* oaccT)
{
    s8_t pb = *(const s8_t*)(lds + (wv * 16 + cc) * PSTRB + KC * 64 + quad * 16);
    u32x2 t00 = tr_read<KC * 4352 +    0>(vaddr);
    u32x2 t01 = tr_read<KC * 4352 +  544>(vaddr);
    u32x2 t10 = tr_read<KC * 4352 + 1088>(vaddr);
    u32x2 t11 = tr_read<KC * 4352 + 1632>(vaddr);
    u32x2 t20 = tr_read<KC * 4352 + 2176>(vaddr);
    u32x2 t21 = tr_read<KC * 4352 + 2720>(vaddr);
    u32x2 t30 = tr_read<KC * 4352 + 3264>(vaddr);
    u32x2 t31 = tr_read<KC * 4352 + 3808>(vaddr);
    asm volatile("s_waitcnt lgkmcnt(0)" ::: "memory");
    __builtin_amdgcn_sched_barrier(0);
    union { u32x2 d[2]; s8_t s; } u0, u1, u2, u3;
    u0.d[0] = t00; u0.d[1] = t01;
    u1.d[0] = t10; u1.d[1] = t11;
    u2.d[0] = t20; u2.d[1] = t21;
    u3.d[0] = t30; u3.d[1] = t31;
    oaccT[0] = __builtin_amdgcn_mfma_f32_16x16x32_bf16(u0.s, pb, oaccT[0], 0, 0, 0);
    oaccT[1] = __builtin_amdgcn_mfma_f32_16x16x32_bf16(u1.s, pb, oaccT[1], 0, 0, 0);
    oaccT[2] = __builtin_amdgcn_mfma_f32_16x16x32_bf16(u2.s, pb, oaccT[2], 0, 0, 0);
    oaccT[3] = __builtin_amdgcn_mfma_f32_16x16x32_bf16(u3.s, pb, oaccT[3], 0, 0, 0);
}

__global__ __launch_bounds__(256, 4) void attn_kernel(
    const float* __restrict__ qk, const float* __restrict__ v,
    const int* __restrict__ st_ws,
    unsigned char* __restrict__ o_ws, float* __restrict__ logits_ws)
{
    __shared__ char lds[LDS_TOT];
    float* nrm_s  = (float*)(lds + OFF_NRM);
    int*   tkx    = (int*)(lds + OFF_TKX);
    float* pinv_s = (float*)(lds + OFF_PINV);

    int tid = threadIdx.x;
    // XCD-contiguous swizzle: resident blocks share one batch's working set.
    int wg = blockIdx.x;
    int orig = ((wg & 7) << 10) + (wg >> 3);
    int c = orig & (CHUNKS - 1);
    int b = orig >> 9;
    int h = c >> 6;
    int sbase = b * (NH * S);
    int cprev = (c + CHUNKS - 1) & (CHUNKS - 1);

    int wv   = tid >> 6;
    int lane = tid & 63;
    int quad = lane >> 4;
    int cc   = lane & 15;
    int s_   = lane & 3;

    // ---- K gather FIRST (coalesced: 4 lanes/row) ----
    int rowA = wv * 32 + (lane >> 2);
    int rowB = rowA + 16;
    int chK  = (wv < 2) ? c : cprev;
    int tokKA = st_ws[sbase + chK * BS + (rowA & 63)];
    int tokKB = st_ws[sbase + chK * BS + (rowB & 63)];
    const float4* kpA = (const float4*)(qk + ((size_t)b * S + tokKA) * D);
    const float4* kpB = (const float4*)(qk + ((size_t)b * S + tokKB) * D);
    float4 kA4[4], kB4[4];
    #pragma unroll
    for (int n = 0; n < 4; ++n) { kA4[n] = kpA[n * 4 + s_]; kB4[n] = kpB[n * 4 + s_]; }

    // ---- V gather SECOND (coalesced; stays in flight under QK) ----
    int prA = wv * 32 + (lane >> 2);      // positions (kappa order)
    int prB = prA + 16;
    int ciA = ((prA & 3) << 4) | (prA >> 3);   // kappa^-1 within-chunk index
    int ciB = ((prB & 3) << 4) | (prB >> 3);
    int chVA = (prA & 4) ? cprev : c;
    int chVB = (prB & 4) ? cprev : c;
    int tokVA = st_ws[sbase + chVA * BS + ciA];
    int tokVB = st_ws[sbase + chVB * BS + ciB];
    const float4* vpA = (const float4*)(v + ((size_t)b * S + tokVA) * D);
    const float4* vpB = (const float4*)(v + ((size_t)b * S + tokVB) * D);
    float4 vA4[4], vB4[4];
    #pragma unroll
    for (int n = 0; n < 4; ++n) { vA4[n] = vpA[n * 4 + s_]; vB4[n] = vpB[n * 4 + s_]; }

    // ---- K process: inv-norms (pre-scaled, rsq) + raw bf16 -> LDS ----
    {
        float ssA = 0.f, ssB = 0.f;
        #pragma unroll
        for (int n = 0; n < 4; ++n) {
            ssA += kA4[n].x*kA4[n].x + kA4[n].y*kA4[n].y
                 + kA4[n].z*kA4[n].z + kA4[n].w*kA4[n].w;
            ssB += kB4[n].x*kB4[n].x + kB4[n].y*kB4[n].y
                 + kB4[n].z*kB4[n].z + kB4[n].w*kB4[n].w;
        }
        ssA += __shfl_xor(ssA, 1, 64); ssA += __shfl_xor(ssA, 2, 64);
        ssB += __shfl_xor(ssB, 1, 64); ssB += __shfl_xor(ssB, 2, 64);
        if (s_ == 0) {
            nrm_s[rowA] = __builtin_amdgcn_rsqf(fmaxf(ssA, 1e-24f)) * 0.18033688f;
            nrm_s[rowB] = __builtin_amdgcn_rsqf(fmaxf(ssB, 1e-24f)) * 0.18033688f;
            tkx[rowA] = tokKA;
            tkx[rowB] = tokKB;
        }
        #pragma unroll
        for (int n = 0; n < 4; ++n) {
            *(uint2*)(lds + rowA * KSTRB + n * 32 + s_ * 8) =
                make_uint2(pack_trunc(kA4[n].x, kA4[n].y),
                           pack_trunc(kA4[n].z, kA4[n].w));
            *(uint2*)(lds + rowB * KSTRB + n * 32 + s_ * 8) =
                make_uint2(pack_trunc(kB4[n].x, kB4[n].y),
                           pack_trunc(kB4[n].z, kB4[n].w));
        }
    }
    BAR_LGKM();   // K/tkx/nrm visible; V loads legally still in flight

    // ---- dots: QK^T via bf16 MFMA (raw x raw) ----
    int qrow = wv * 16 + cc;
    f4_t acc[8];
    #pragma unroll
    for (int t = 0; t < 8; ++t) acc[t] = (f4_t){0.f,0.f,0.f,0.f};

    __builtin_amdgcn_s_setprio(1);
    #pragma unroll
    for (int kc = 0; kc < 2; ++kc) {
        int aoff = kc * 64 + quad * 16;
        s8_t av = *(const s8_t*)(lds + qrow * KSTRB + aoff);
        #pragma unroll
        for (int t = 0; t < 8; ++t) {
            s8_t bv = *(const s8_t*)(lds + (t * 16 + cc) * KSTRB + aoff);
            acc[t] = __builtin_amdgcn_mfma_f32_16x16x32_bf16(av, bv, acc[t], 0, 0, 0);
        }
    }
    __builtin_amdgcn_s_setprio(0);

    // ---- pack + write V (tr-subtiled; loads arrived under QK) ----
    {
        int kcA = prA >> 5, qA = (prA >> 3) & 3, rA = (prA >> 2) & 1, jA = prA & 3;
        int kcB = prB >> 5, qB = (prB >> 3) & 3, rB = (prB >> 2) & 1, jB = prB & 3;
        #pragma unroll
        for (int n = 0; n < 4; ++n) {
            *(uint2*)(lds + OFF_VT + (kcA * 8 + n * 2 + rA) * 544
                      + qA * 128 + jA * 32 + s_ * 8) =
                make_uint2(pack_trunc(vA4[n].x, vA4[n].y),
                           pack_trunc(vA4[n].z, vA4[n].w));
            *(uint2*)(lds + OFF_VT + (kcB * 8 + n * 2 + rB) * 544
                      + qB * 128 + jB * 32 + s_ * 8) =
                make_uint2(pack_trunc(vB4[n].x, vB4[n].y),
                           pack_trunc(vB4[n].z, vB4[n].w));
        }
    }

    // ---- HOISTED barrier: all K-reads done (QK above), V-writes done.
    // Everything below is wave-private or fire-and-forget.
    BAR_LGKM();

    // ---- max-free softmax (log2 domain, bounded exponents) ----
    float invsc[8];
    #pragma unroll
    for (int t = 0; t < 8; ++t)
        invsc[t] = nrm_s[t * 16 + cc];     // already 0.125*log2(e)/|k|

    #pragma unroll
    for (int t = 0; t < 8; ++t) {
        #pragma unroll
        for (int g = 0; g < 4; ++g)
            acc[t][g] = __builtin_amdgcn_exp2f(acc[t][g] * invsc[t]);
        if (t == wv) {          // static self-mask: p = 0 (scalar-uniform branch)
            #pragma unroll
            for (int g = 0; g < 4; ++g)
                if (cc == quad * 4 + g) acc[t][g] = 0.f;
        }
    }

    // ---- P -> bf16 LDS in kappa order (wave-private rows; no barrier) ----
    #pragma unroll
    for (int g = 0; g < 4; ++g) {
        int q = wv * 16 + quad * 4 + g;
        uint4 w;
        w.x = pack_trunc(acc[0][g], acc[1][g]);   // positions 8cc+0..7 = keys t*16+cc
        w.y = pack_trunc(acc[2][g], acc[3][g]);
        w.z = pack_trunc(acc[4][g], acc[5][g]);
        w.w = pack_trunc(acc[6][g], acc[7][g]);
        *(uint4*)(lds + q * PSTRB + cc * 16) = w;
    }

    // ---- row sums + logits + pinv ----
    float sm[4] = {0.f, 0.f, 0.f, 0.f};
    #pragma unroll
    for (int t = 0; t < 8; ++t)
        #pragma unroll
        for (int g = 0; g < 4; ++g) sm[g] += acc[t][g];
    #pragma unroll
    for (int msk = 1; msk <= 8; msk <<= 1)
        #pragma unroll
        for (int g = 0; g < 4; ++g) sm[g] += __shfl_xor(sm[g], msk, 64);

    if (cc == 0) {
        #pragma unroll
        for (int g = 0; g < 4; ++g) {
            int q = wv * 16 + quad * 4 + g;
            int tq = tkx[q];
            pinv_s[q] = __builtin_amdgcn_rcpf(sm[g]);
            logits_ws[sbase + h * S + tq] = 0.69314718f * __log2f(sm[g]);
        }
    }

    // ---- PV as O^T = V^T * P via tr reads ----
    f4_t oaccT[4];
    #pragma unroll
    for (int n = 0; n < 4; ++n) oaccT[n] = (f4_t){0.f,0.f,0.f,0.f};

    unsigned vaddr = (unsigned)(unsigned long long)(lds + OFF_VT)
                   + (unsigned)lane * 8u;

    __builtin_amdgcn_s_setprio(1);
    pv_step<0>(lds, vaddr, wv, cc, quad, oaccT);
    pv_step<1>(lds, vaddr, wv, cc, quad, oaccT);
    pv_step<2>(lds, vaddr, wv, cc, quad, oaccT);
    pv_step<3>(lds, vaddr, wv, cc, quad, oaccT);
    __builtin_amdgcn_s_setprio(0);

    // ---- write O (fp8 e4m3, scaled by deferred pinv): 4 x 4B stores ----
    {
        int q = wv * 16 + cc;
        int tok = tkx[q];                 // tkx region not overlaid by P
        float pq = pinv_s[q];
        unsigned char* op = o_ws + ((size_t)(sbase + h * S + tok)) * D + quad * 4;
        #pragma unroll
        for (int n = 0; n < 4; ++n) {
            int w = 0;
            w = __builtin_amdgcn_cvt_pk_fp8_f32(oaccT[n][0] * pq,
                                                oaccT[n][1] * pq, w, false);
            w = __builtin_amdgcn_cvt_pk_fp8_f32(oaccT[n][2] * pq,
                                                oaccT[n][3] * pq, w, true);
            *(unsigned int*)(op + n * 16) = (unsigned int)w;
        }
    }
}

// ---------------------------------------------------------------------------
// Kernel 4: combine hash rounds with softmax(logits) weights. o_ws is fp8
// e4m3 (64 B/token-row). 16 dims/thread keeps 16B loads; 1024 blocks with
// the same XCD-affinity map as attn's writer.
// ---------------------------------------------------------------------------
__global__ __launch_bounds__(256) void combine_kernel(
    const unsigned char* __restrict__ o_ws, const float* __restrict__ logits_ws,
    float* __restrict__ out)
{
    int wg = blockIdx.x;                       // 1024 blocks
    int b  = ((wg & 7) << 1) | ((wg >> 3) & 1);
    int tb = wg >> 4;                          // 0..63 block-within-batch
    int tid = threadIdx.x;
    int t = tb * 64 + (tid >> 2);
    int dq = tid & 3;                          // 16-dim quarter
    int token = (b << 12) + t;
    int base = b * (NH * S) + t;

    float l[8];
    #pragma unroll
    for (int hh = 0; hh < 8; ++hh) l[hh] = logits_ws[base + hh * S];
    float m = l[0];
    #pragma unroll
    for (int hh = 1; hh < 8; ++hh) m = fmaxf(m, l[hh]);
    float w[8]; float ssum = 0.f;
    #pragma unroll
    for (int hh = 0; hh < 8; ++hh) { w[hh] = __expf(l[hh] - m); ssum += w[hh]; }
    float inv = __builtin_amdgcn_rcpf(ssum);

    float accv[16];
    #pragma unroll
    for (int e = 0; e < 16; ++e) accv[e] = 0.f;
    #pragma unroll
    for (int hh = 0; hh < 8; ++hh) {
        uint4 pk = *(const uint4*)(o_ws + ((size_t)(base + hh * S)) * D + dq * 16);
        float wh = w[hh] * inv;
        unsigned int ws_[4] = {pk.x, pk.y, pk.z, pk.w};
        #pragma unroll
        for (int e = 0; e < 4; ++e) {
            f2_t lo = __builtin_amdgcn_cvt_pk_f32_fp8((int)ws_[e], false);
            f2_t hi = __builtin_amdgcn_cvt_pk_f32_fp8((int)ws_[e], true);
            accv[4*e+0] += wh * lo[0];
            accv[4*e+1] += wh * lo[1];
            accv[4*e+2] += wh * hi[0];
            accv[4*e+3] += wh * hi[1];
        }
    }
    float4* op = (float4*)(out + (size_t)token * D + dq * 16);
    #pragma unroll
    for (int e4 = 0; e4 < 4; ++e4)
        op[e4] = make_float4(accv[e4*4+0], accv[e4*4+1],
                             accv[e4*4+2], accv[e4*4+3]);
}

// ---------------------------------------------------------------------------
extern "C" void kernel_launch(void* const* d_in, const int* in_sizes, int n_in,
                              void* d_out, int out_size, void* d_ws, size_t ws_size,
                              hipStream_t stream) {
    const float* qk  = (const float*)d_in[0];
    const float* v   = (const float*)d_in[1];
    const float* rot = (const float*)d_in[2];

    float* out         = (float*)d_out;
    float* out_buckets = out + (size_t)B * S * D;

    int*   bucket_ws = (int*)d_ws;                              // 524288 ints
    int*   st_ws     = bucket_ws + (size_t)B * NH * S;          // 524288 ints
    float* logits_ws = (float*)(st_ws + (size_t)B * NH * S);    // 524288 f32
    unsigned char* o_ws = (unsigned char*)(logits_ws + (size_t)B * NH * S); // 32 MB fp8
    unsigned char* flag_ws = o_ws + (size_t)B * NH * S * D;     // 512 KB

    hash_kernel<<<B * 32, 256, 0, stream>>>(qk, rot, out_buckets, bucket_ws,
                                            flag_ws);
    sort_kernel<<<B * NH, 1024, 0, stream>>>(bucket_ws, st_ws, qk, rot,
                                             flag_ws, out_buckets);
    attn_kernel<<<B * CHUNKS, 256, 0, stream>>>(qk, v, st_ws, o_ws, logits_ws);
    combine_kernel<<<(B * S * 4) / 256, 256, 0, stream>>>(o_ws, logits_ws, out);
}